// Round 3
// baseline (634.775 us; speedup 1.0000x reference)
//
#include <hip/hip_runtime.h>
#include <hip/hip_bf16.h>

#define BS 16384    // B*S tokens
#define HDIM 4096   // hidden dim
#define NE 64       // experts
#define KC 64       // K-chunk per LDS stage
#define TT 32       // tokens per block (K1)
#define CAP 512     // max boundary candidates per expert
#define DELTA 2e-3f // fp32/bf16-split GEMM error margin (actual err ~1e-4)
#define NBIN 65536  // histogram bins = top 16 bits of sortable key

typedef __bf16 bf16x8 __attribute__((ext_vector_type(8)));
typedef float f32x4 __attribute__((ext_vector_type(4)));
union Frag { uint4 q; bf16x8 v; };

__device__ inline unsigned f2key(float f) {
    unsigned u = __float_as_uint(f);
    return (u & 0x80000000u) ? ~u : (u | 0x80000000u);
}
__device__ inline float key2f(unsigned k) {
    unsigned u = (k & 0x80000000u) ? (k ^ 0x80000000u) : ~k;
    return __uint_as_float(u);
}
// pack bf16(a) into low16, bf16(b) into high16 (truncation)
__device__ inline unsigned pack_hi(float a, float b) {
    return (__float_as_uint(a) >> 16) | (__float_as_uint(b) & 0xFFFF0000u);
}
__device__ inline float bf16_resid(float a) {  // a - truncate_bf16(a), exact
    return a - __uint_as_float(__float_as_uint(a) & 0xFFFF0000u);
}

// ---------------------------------------------------------------------------
// K0: zero the 16 MB histogram + imp accumulator; convert W -> bf16 hi/lo.
// ---------------------------------------------------------------------------
__global__ __launch_bounds__(256) void k0_init(const float* __restrict__ W,
                                               unsigned short* __restrict__ Wh,
                                               unsigned short* __restrict__ Wl,
                                               unsigned* __restrict__ hist,
                                               double* __restrict__ imp_g) {
    const int b = blockIdx.x, t = threadIdx.x;
    const size_t base = ((size_t)b * 256 + t) * 8;   // 2048*256*8 = 4M u32
    uint4 z = {0, 0, 0, 0};
    *(uint4*)(hist + base) = z;
    *(uint4*)(hist + base + 4) = z;
    if (b == 0 && t < 64) imp_g[t] = 0.0;
    if (b < 256) {
        const size_t f = ((size_t)b * 256 + t) * 4;  // 256*256*4 = 262144 = NE*HDIM
        float4 w = *(const float4*)(W + f);
        uint2 hh, ll;
        hh.x = pack_hi(w.x, w.y); hh.y = pack_hi(w.z, w.w);
        ll.x = pack_hi(bf16_resid(w.x), bf16_resid(w.y));
        ll.y = pack_hi(bf16_resid(w.z), bf16_resid(w.w));
        *(uint2*)(Wh + f) = hh;
        *(uint2*)(Wl + f) = ll;
    }
}

// ---------------------------------------------------------------------------
// K1: logits = A @ W^T via bf16-split MFMA (3 mfma per tile: AhBh+AlBh+AhBl).
// Block: 32 tokens x 64 experts, 256 thr (4 waves, wave = 2 M-tiles x 16 exp).
// Epilogue: write Lg (token-major fp32), KeyT (expert-major sortable u32),
// and atomically histogram key>>16 per expert.
// ---------------------------------------------------------------------------
__global__ __launch_bounds__(256, 2) void k1_gemm(const float* __restrict__ A,
                                                  const unsigned short* __restrict__ Wh,
                                                  const unsigned short* __restrict__ Wl,
                                                  float* __restrict__ Lg,
                                                  unsigned* __restrict__ KeyT,
                                                  unsigned* __restrict__ hist) {
    __shared__ __align__(16) unsigned short As_h[TT][72], As_l[TT][72];
    __shared__ __align__(16) unsigned short Ws_h[64][72], Ws_l[64][72];

    const int tid = threadIdx.x;
    const int T0 = blockIdx.x * TT;
    const int arow = tid >> 3, aseg = tid & 7;
    const float* Ap = A + (size_t)(T0 + arow) * HDIM + aseg * 8;

    const int lane = tid & 63, w = tid >> 6;
    const int m = lane & 15, q = lane >> 4;
    const int en = w * 16;

    f32x4 acc0 = {0.f, 0.f, 0.f, 0.f}, acc1 = {0.f, 0.f, 0.f, 0.f};

    float4 pa0, pa1;
    uint4 pw[4];
    pa0 = *(const float4*)(Ap);
    pa1 = *(const float4*)(Ap + 4);
#pragma unroll
    for (int i = 0; i < 4; ++i) {
        const int u = i * 256 + tid;
        const unsigned short* Wm = (u >= 512) ? Wl : Wh;
        const int r = (u >> 3) & 63, blk = u & 7;
        pw[i] = *(const uint4*)(Wm + (size_t)r * HDIM + blk * 8);
    }

    for (int c = 0; c < HDIM / KC; ++c) {
        __syncthreads();
        {
            uint4 H, L;
            H.x = pack_hi(pa0.x, pa0.y); H.y = pack_hi(pa0.z, pa0.w);
            H.z = pack_hi(pa1.x, pa1.y); H.w = pack_hi(pa1.z, pa1.w);
            L.x = pack_hi(bf16_resid(pa0.x), bf16_resid(pa0.y));
            L.y = pack_hi(bf16_resid(pa0.z), bf16_resid(pa0.w));
            L.z = pack_hi(bf16_resid(pa1.x), bf16_resid(pa1.y));
            L.w = pack_hi(bf16_resid(pa1.z), bf16_resid(pa1.w));
            *(uint4*)(&As_h[arow][aseg * 8]) = H;
            *(uint4*)(&As_l[arow][aseg * 8]) = L;
#pragma unroll
            for (int i = 0; i < 4; ++i) {
                const int u = i * 256 + tid;
                unsigned short* dst = (u >= 512) ? &Ws_l[0][0] : &Ws_h[0][0];
                const int r = (u >> 3) & 63, blk = u & 7;
                *(uint4*)(dst + r * 72 + blk * 8) = pw[i];
            }
        }
        __syncthreads();
        if (c + 1 < HDIM / KC) {
            const int c0 = (c + 1) * KC;
            pa0 = *(const float4*)(Ap + c0);
            pa1 = *(const float4*)(Ap + c0 + 4);
#pragma unroll
            for (int i = 0; i < 4; ++i) {
                const int u = i * 256 + tid;
                const unsigned short* Wm = (u >= 512) ? Wl : Wh;
                const int r = (u >> 3) & 63, blk = u & 7;
                pw[i] = *(const uint4*)(Wm + (size_t)r * HDIM + c0 + blk * 8);
            }
        }
#pragma unroll
        for (int k2 = 0; k2 < 2; ++k2) {
            const int ko = k2 * 32 + q * 8;
            Frag ah0, ah1, al0, al1, bh, bl;
            ah0.q = *(const uint4*)(&As_h[m][ko]);
            ah1.q = *(const uint4*)(&As_h[m + 16][ko]);
            al0.q = *(const uint4*)(&As_l[m][ko]);
            al1.q = *(const uint4*)(&As_l[m + 16][ko]);
            bh.q  = *(const uint4*)(&Ws_h[en + m][ko]);
            bl.q  = *(const uint4*)(&Ws_l[en + m][ko]);
            acc0 = __builtin_amdgcn_mfma_f32_16x16x32_bf16(ah0.v, bh.v, acc0, 0, 0, 0);
            acc1 = __builtin_amdgcn_mfma_f32_16x16x32_bf16(ah1.v, bh.v, acc1, 0, 0, 0);
            acc0 = __builtin_amdgcn_mfma_f32_16x16x32_bf16(al0.v, bh.v, acc0, 0, 0, 0);
            acc1 = __builtin_amdgcn_mfma_f32_16x16x32_bf16(al1.v, bh.v, acc1, 0, 0, 0);
            acc0 = __builtin_amdgcn_mfma_f32_16x16x32_bf16(ah0.v, bl.v, acc0, 0, 0, 0);
            acc1 = __builtin_amdgcn_mfma_f32_16x16x32_bf16(ah1.v, bl.v, acc1, 0, 0, 0);
        }
    }

#pragma unroll
    for (int mt = 0; mt < 2; ++mt) {
        f32x4 acc = mt ? acc1 : acc0;
        const int e = en + m;  // C/D: col = lane&15
#pragma unroll
        for (int r = 0; r < 4; ++r) {
            const int t = T0 + mt * 16 + q * 4 + r;  // C/D: row = quad*4+reg
            const float val = acc[r];
            Lg[(size_t)t * NE + e] = val;
            const unsigned key = f2key(val);
            KeyT[(size_t)e * BS + t] = key;
            atomicAdd(&hist[(size_t)e * NBIN + (key >> 16)], 1u);
        }
    }
}

// ---------------------------------------------------------------------------
// K2: per-expert, find the histogram bin B containing the C-th largest key
// (suffix scan), set cuts at bin edges +/- DELTA, then one pass over the key
// column: count definite-ins (key > khi), collect candidates in [klo,khi].
// ---------------------------------------------------------------------------
__global__ __launch_bounds__(1024) void k2_select(const unsigned* __restrict__ KeyT,
                                                  const unsigned* __restrict__ hist,
                                                  const int* __restrict__ Cptr,
                                                  unsigned* __restrict__ khi_g,
                                                  int* __restrict__ needed_g,
                                                  int* __restrict__ ncand_g,
                                                  int* __restrict__ cand_g,
                                                  unsigned* __restrict__ win_g) {
    const int e = blockIdx.x, tid = threadIdx.x;
    const int C = *Cptr;
    const unsigned* he = hist + (size_t)e * NBIN;
    __shared__ int ls[1024];
    __shared__ int s_tstar, s_after, s_B, s_nd, s_nc;

    if (tid < 512) win_g[(size_t)e * 512 + tid] = 0u;
    if (tid == 0) { s_nd = 0; s_nc = 0; s_tstar = 0; s_after = 0; s_B = 0; }

    int s = 0;
#pragma unroll
    for (int i = 0; i < 16; ++i) {
        uint4 v = *(const uint4*)(he + tid * 64 + i * 4);
        s += (int)(v.x + v.y + v.z + v.w);
    }
    ls[tid] = s;
    __syncthreads();
    for (int off = 1; off < 1024; off <<= 1) {
        int v = (tid + off < 1024) ? ls[tid + off] : 0;
        __syncthreads();
        ls[tid] += v;
        __syncthreads();
    }
    if (ls[tid] >= C && (tid == 1023 || ls[tid + 1] < C)) {
        s_tstar = tid;
        s_after = (tid == 1023) ? 0 : ls[tid + 1];
    }
    __syncthreads();
    const int tstar = s_tstar, after = s_after;
    if (tid < 64) ls[tid] = (int)he[tstar * 64 + tid];
    __syncthreads();
    for (int off = 1; off < 64; off <<= 1) {
        int v = 0;
        if (tid < 64 && tid + off < 64) v = ls[tid + off];
        __syncthreads();
        if (tid < 64) ls[tid] += v;
        __syncthreads();
    }
    if (tid < 64) {
        const int sfx = ls[tid] + after;
        const int nxt = ((tid == 63) ? 0 : ls[tid + 1]) + after;
        if (sfx >= C && nxt < C) s_B = tstar * 64 + tid;
    }
    __syncthreads();
    const int B = s_B;
    const unsigned khi = (B >= 65535) ? 0xFFFFFFFFu
                                      : f2key(key2f((unsigned)(B + 1) << 16) + DELTA);
    const unsigned klo = f2key(key2f((unsigned)B << 16) - DELTA);

    const unsigned* col = KeyT + (size_t)e * BS;
    int nd_loc = 0;
    for (int i = 0; i < BS / 1024; ++i) {
        const int t = i * 1024 + tid;
        const unsigned k = col[t];
        nd_loc += (k > khi);
        if (k >= klo && k <= khi) {
            const int p = atomicAdd(&s_nc, 1);
            if (p < CAP) cand_g[(size_t)e * CAP + p] = t;
        }
    }
    atomicAdd(&s_nd, nd_loc);
    __syncthreads();
    if (tid == 0) {
        khi_g[e] = khi;
        needed_g[e] = C - s_nd;
        ncand_g[e] = (s_nc < CAP) ? s_nc : CAP;
    }
}

// ---------------------------------------------------------------------------
// K2b: exact fp64 dots for boundary candidates (wave-parallel); pick
// top-'needed' by (fp64 desc, idx asc); set winner bits.
// ---------------------------------------------------------------------------
__global__ __launch_bounds__(256) void k2b_resolve(const float* __restrict__ A,
                                                   const float* __restrict__ W,
                                                   const int* __restrict__ needed_g,
                                                   const int* __restrict__ ncand_g,
                                                   const int* __restrict__ cand_g,
                                                   unsigned* __restrict__ win_g) {
    const int e = blockIdx.x, tid = threadIdx.x, w = tid >> 6, lane = tid & 63;
    int n = ncand_g[e]; if (n > CAP) n = CAP;
    int need = needed_g[e]; if (need > n) need = n; if (need < 0) need = 0;
    __shared__ double sval[CAP];
    __shared__ int sidx[CAP];
    const float* Wr = W + (size_t)e * HDIM;
    for (int c = w; c < n; c += 4) {
        const int t = cand_g[(size_t)e * CAP + c];
        const float* Ar = A + (size_t)t * HDIM;
        double ps = 0.0;
#pragma unroll 8
        for (int j = 0; j < HDIM / 64; ++j)
            ps += (double)Ar[j * 64 + lane] * (double)Wr[j * 64 + lane];
#pragma unroll
        for (int off = 32; off; off >>= 1) ps += __shfl_xor(ps, off);
        if (lane == 0) { sval[c] = ps; sidx[c] = t; }
    }
    __syncthreads();
    if (tid == 0) {
        for (int s = 0; s < need; ++s) {
            int best = -1;
            for (int c = 0; c < n; ++c) {
                if (sidx[c] < 0) continue;
                if (best < 0 || sval[c] > sval[best] ||
                    (sval[c] == sval[best] && sidx[c] < sidx[best]))
                    best = c;
            }
            const int t = sidx[best];
            win_g[(size_t)e * 512 + (t >> 5)] |= (1u << (t & 31));
            sidx[best] = -1;
        }
    }
}

// ---------------------------------------------------------------------------
// K3: per-token softmax+mask+renorm in one reduction pass (no max-sub needed,
// |logit| <~ 7). map = (key > khi) | winner bit. fp64 importance via atomics.
// ---------------------------------------------------------------------------
__global__ __launch_bounds__(256) void k3_softmax(const float* __restrict__ Lg,
                                                  const unsigned* __restrict__ khi_g,
                                                  const unsigned* __restrict__ win_g,
                                                  float* __restrict__ probs,
                                                  float* __restrict__ out_map,
                                                  double* __restrict__ imp_g) {
    const int tid = threadIdx.x, w = tid >> 6, e = tid & 63, b = blockIdx.x;
    __shared__ unsigned skhi[64];
    __shared__ double sim[4][64];
    if (tid < 64) skhi[tid] = khi_g[tid];
    __syncthreads();
    const unsigned kh = skhi[e];
    double accim = 0.0;
#pragma unroll
    for (int it = 0; it < 4; ++it) {
        const int t = b * 16 + w * 4 + it;
        const float x = Lg[(size_t)t * NE + e];
        const unsigned key = f2key(x);
        float mfl;
        if (key > kh) mfl = 1.f;
        else mfl = (float)((win_g[(size_t)e * 512 + (t >> 5)] >> (t & 31)) & 1u);
        const float ev = expf(x);
        const float evm = ev * mfl;
        float s1 = ev, s2 = evm;
#pragma unroll
        for (int off = 32; off; off >>= 1) {
            s1 += __shfl_xor(s1, off);
            s2 += __shfl_xor(s2, off);
        }
        const float o = evm / (s2 + 1e-6f * s1);
        probs[(size_t)t * NE + e] = o;
        out_map[(size_t)t * NE + e] = mfl;
        accim += (double)o;
    }
    sim[w][e] = accim;
    __syncthreads();
    if (w == 0) atomicAdd(&imp_g[e], sim[0][e] + sim[1][e] + sim[2][e] + sim[3][e]);
}

// ---------------------------------------------------------------------------
// K4: aux = (std(importance,ddof=1)/(mean+eps))^2 ; load_loss == 0 exactly.
// ---------------------------------------------------------------------------
__global__ __launch_bounds__(64) void k4_aux(const double* __restrict__ imp_g,
                                             float* __restrict__ out_aux) {
    const int e = threadIdx.x;
    const double v = imp_g[e];
    double s = v;
#pragma unroll
    for (int off = 32; off; off >>= 1) s += __shfl_xor(s, off);
    const double mean = s / 64.0;
    const double d = v - mean;
    double ss = d * d;
#pragma unroll
    for (int off = 32; off; off >>= 1) ss += __shfl_xor(ss, off);
    if (e == 0) {
        const double var = ss / 63.0;
        const double dn = mean + 1e-6;
        out_aux[0] = (float)(var / (dn * dn));
    }
}

extern "C" void kernel_launch(void* const* d_in, const int* in_sizes, int n_in,
                              void* d_out, int out_size, void* d_ws, size_t ws_size,
                              hipStream_t stream) {
    const float* A = (const float*)d_in[0];
    const float* W = (const float*)d_in[1];
    const int* Cptr = (const int*)d_in[2];

    float* out_probs = (float*)d_out;
    float* out_map = out_probs + (size_t)BS * NE;
    float* out_aux = out_map + (size_t)BS * NE;

    char* wsb = (char*)d_ws;
    float*          Lg     = (float*)wsb;                                   // 4 MB
    unsigned*       KeyT   = (unsigned*)(wsb + (4ull << 20));               // 4 MB
    unsigned*       hist   = (unsigned*)(wsb + (8ull << 20));               // 16 MB
    unsigned short* Wh     = (unsigned short*)(wsb + (24ull << 20));        // 512 KB
    unsigned short* Wl     = (unsigned short*)(wsb + (24ull << 20) + (512ull << 10));
    int*            cand   = (int*)(wsb + (25ull << 20));                   // 128 KB
    unsigned*       win    = (unsigned*)(wsb + (25ull << 20) + (128ull << 10));
    unsigned*       khi_g  = (unsigned*)(wsb + (25ull << 20) + (256ull << 10));
    int*            needed = (int*)(wsb + (25ull << 20) + (257ull << 10));
    int*            ncand  = (int*)(wsb + (25ull << 20) + (258ull << 10));
    double*         imp_g  = (double*)(wsb + (25ull << 20) + (259ull << 10));

    k0_init<<<2048, 256, 0, stream>>>(W, Wh, Wl, hist, imp_g);
    k1_gemm<<<BS / TT, 256, 0, stream>>>(A, Wh, Wl, Lg, KeyT, hist);
    k2_select<<<NE, 1024, 0, stream>>>(KeyT, hist, Cptr, khi_g, needed, ncand, cand, win);
    k2b_resolve<<<NE, 256, 0, stream>>>(A, W, needed, ncand, cand, win);
    k3_softmax<<<BS / 16, 256, 0, stream>>>(Lg, khi_g, win, out_probs, out_map, imp_g);
    k4_aux<<<1, 64, 0, stream>>>(imp_g, out_aux);
}

// Round 4
// 473.940 us; speedup vs baseline: 1.3394x; 1.3394x over previous
//
#include <hip/hip_runtime.h>
#include <hip/hip_bf16.h>

#define BS 16384    // B*S tokens
#define HDIM 4096   // hidden dim
#define NE 64       // experts
#define KC 64       // K-chunk per LDS stage
#define TT 64       // tokens per block (K1)
#define CAP 512     // max boundary candidates per expert
#define DELTA 2e-3f // bf16-split GEMM error margin (actual err ~2e-5)

typedef __bf16 bf16x8 __attribute__((ext_vector_type(8)));
typedef float f32x4 __attribute__((ext_vector_type(4)));
union Frag { uint4 q; bf16x8 v; };

__device__ inline unsigned f2key(float f) {
    unsigned u = __float_as_uint(f);
    return (u & 0x80000000u) ? ~u : (u | 0x80000000u);
}
__device__ inline float key2f(unsigned k) {
    unsigned u = (k & 0x80000000u) ? (k ^ 0x80000000u) : ~k;
    return __uint_as_float(u);
}
__device__ inline unsigned pack_hi(float a, float b) {  // bf16(a)|bf16(b)<<16 (trunc)
    return (__float_as_uint(a) >> 16) | (__float_as_uint(b) & 0xFFFF0000u);
}
__device__ inline float bf16_resid(float a) {  // a - trunc_bf16(a), exact
    return a - __uint_as_float(__float_as_uint(a) & 0xFFFF0000u);
}

// ---------------------------------------------------------------------------
// K0: convert W -> bf16 hi/lo; zero winner bitmap + importance accumulator.
// ---------------------------------------------------------------------------
__global__ __launch_bounds__(256) void k0_init(const float* __restrict__ W,
                                               unsigned short* __restrict__ Wh,
                                               unsigned short* __restrict__ Wl,
                                               unsigned* __restrict__ win_g,
                                               double* __restrict__ imp_g) {
    const int gtid = blockIdx.x * 256 + threadIdx.x;  // 0..65535
    const size_t f = (size_t)gtid * 4;                // covers NE*HDIM = 262144
    float4 w = *(const float4*)(W + f);
    uint2 hh, ll;
    hh.x = pack_hi(w.x, w.y); hh.y = pack_hi(w.z, w.w);
    ll.x = pack_hi(bf16_resid(w.x), bf16_resid(w.y));
    ll.y = pack_hi(bf16_resid(w.z), bf16_resid(w.w));
    *(uint2*)(Wh + f) = hh;
    *(uint2*)(Wl + f) = ll;
    if (gtid < NE * CAP) win_g[gtid] = 0u;  // 32768 u32 = 128 KB bitmap
    if (gtid < NE) imp_g[gtid] = 0.0;
}

// ---------------------------------------------------------------------------
// K1: logits = A @ W^T via bf16-split MFMA (AhBh+AlBh+AhBl, 16x16x32).
// 64x64 tile, 512 thr (8 waves, 2x2 M/N wave split), double-buffered LDS
// (one __syncthreads per chunk), register prefetch. Epilogue: Lg token-major
// + KeyT expert-major via LDS transpose (coalesced 256 B/expert/block).
// ---------------------------------------------------------------------------
__global__ __launch_bounds__(512, 1) void k1_gemm(const float* __restrict__ A,
                                                  const unsigned short* __restrict__ Wh,
                                                  const unsigned short* __restrict__ Wl,
                                                  float* __restrict__ Lg,
                                                  unsigned* __restrict__ KeyT) {
    // per buffer (18432 shorts): As_h[64][72] @0, As_l @4608, Ws_h @9216, Ws_l @13824
    __shared__ __align__(16) unsigned short sbuf[2 * 18432];  // 73728 B

    const int tid = threadIdx.x;
    const int T0 = blockIdx.x * TT;

    const int arow = tid >> 3, aseg = tid & 7;  // A staging: row, 8-float seg
    const int wr = (tid >> 3) & 63, wblk = tid & 7;  // W staging

    const int lane = tid & 63, w = tid >> 6;
    const int m = lane & 15, q = lane >> 4;
    const int wm = w & 3;   // M tile (16 tokens)
    const int wn = w >> 2;  // N half (32 experts)

    const float* Aprow = A + (size_t)(T0 + arow) * HDIM + aseg * 8;
    const unsigned short* Whrow = Wh + (size_t)wr * HDIM + wblk * 8;
    const unsigned short* Wlrow = Wl + (size_t)wr * HDIM + wblk * 8;

    f32x4 acc[2] = {{0.f, 0.f, 0.f, 0.f}, {0.f, 0.f, 0.f, 0.f}};

    float4 pa0 = *(const float4*)(Aprow);
    float4 pa1 = *(const float4*)(Aprow + 4);
    uint4 pw0 = *(const uint4*)(Whrow);
    uint4 pw1 = *(const uint4*)(Wlrow);

    // stage chunk 0 into buffer 0
    {
        unsigned short* B = sbuf;
        uint4 H, L;
        H.x = pack_hi(pa0.x, pa0.y); H.y = pack_hi(pa0.z, pa0.w);
        H.z = pack_hi(pa1.x, pa1.y); H.w = pack_hi(pa1.z, pa1.w);
        L.x = pack_hi(bf16_resid(pa0.x), bf16_resid(pa0.y));
        L.y = pack_hi(bf16_resid(pa0.z), bf16_resid(pa0.w));
        L.z = pack_hi(bf16_resid(pa1.x), bf16_resid(pa1.y));
        L.w = pack_hi(bf16_resid(pa1.z), bf16_resid(pa1.w));
        *(uint4*)(B + arow * 72 + aseg * 8) = H;
        *(uint4*)(B + 4608 + arow * 72 + aseg * 8) = L;
        *(uint4*)(B + 9216 + wr * 72 + wblk * 8) = pw0;
        *(uint4*)(B + 13824 + wr * 72 + wblk * 8) = pw1;
    }

    for (int c = 0; c < HDIM / KC; ++c) {
        if (c + 1 < HDIM / KC) {  // issue prefetch for chunk c+1
            const int c0 = (c + 1) * KC;
            pa0 = *(const float4*)(Aprow + c0);
            pa1 = *(const float4*)(Aprow + c0 + 4);
            pw0 = *(const uint4*)(Whrow + c0);
            pw1 = *(const uint4*)(Wlrow + c0);
        }
        __syncthreads();  // buf[c&1] visible; prior reads of buf[(c+1)&1] done
        {
            const unsigned short* B = sbuf + (c & 1) * 18432;
            const unsigned short* Ash = B + (wm * 16 + m) * 72;
            const unsigned short* Asl = Ash + 4608;
#pragma unroll
            for (int kh = 0; kh < 2; ++kh) {
                const int ko = kh * 32 + q * 8;
                Frag ah, al;
                ah.q = *(const uint4*)(Ash + ko);
                al.q = *(const uint4*)(Asl + ko);
#pragma unroll
                for (int nt = 0; nt < 2; ++nt) {
                    const int er = wn * 32 + nt * 16 + m;
                    Frag bh, bl;
                    bh.q = *(const uint4*)(B + 9216 + er * 72 + ko);
                    bl.q = *(const uint4*)(B + 13824 + er * 72 + ko);
                    acc[nt] = __builtin_amdgcn_mfma_f32_16x16x32_bf16(ah.v, bh.v, acc[nt], 0, 0, 0);
                    acc[nt] = __builtin_amdgcn_mfma_f32_16x16x32_bf16(al.v, bh.v, acc[nt], 0, 0, 0);
                    acc[nt] = __builtin_amdgcn_mfma_f32_16x16x32_bf16(ah.v, bl.v, acc[nt], 0, 0, 0);
                }
            }
        }
        if (c + 1 < HDIM / KC) {  // stage chunk c+1 into the other buffer
            unsigned short* B = sbuf + ((c + 1) & 1) * 18432;
            uint4 H, L;
            H.x = pack_hi(pa0.x, pa0.y); H.y = pack_hi(pa0.z, pa0.w);
            H.z = pack_hi(pa1.x, pa1.y); H.w = pack_hi(pa1.z, pa1.w);
            L.x = pack_hi(bf16_resid(pa0.x), bf16_resid(pa0.y));
            L.y = pack_hi(bf16_resid(pa0.z), bf16_resid(pa0.w));
            L.z = pack_hi(bf16_resid(pa1.x), bf16_resid(pa1.y));
            L.w = pack_hi(bf16_resid(pa1.z), bf16_resid(pa1.w));
            *(uint4*)(B + arow * 72 + aseg * 8) = H;
            *(uint4*)(B + 4608 + arow * 72 + aseg * 8) = L;
            *(uint4*)(B + 9216 + wr * 72 + wblk * 8) = pw0;
            *(uint4*)(B + 13824 + wr * 72 + wblk * 8) = pw1;
        }
    }

    // Epilogue: Lg direct, KeyT via LDS transpose
    __syncthreads();
    float* Sc = (float*)sbuf;  // [64][68]
#pragma unroll
    for (int nt = 0; nt < 2; ++nt) {
        const int e = wn * 32 + nt * 16 + m;
#pragma unroll
        for (int r = 0; r < 4; ++r) {
            const int tl = wm * 16 + q * 4 + r;
            const float v = acc[nt][r];
            Sc[tl * 68 + e] = v;
            Lg[(size_t)(T0 + tl) * NE + e] = v;
        }
    }
    __syncthreads();
    {
        const int e = tid >> 3, jj = tid & 7;  // 8 tokens per thread
        unsigned kk[8];
#pragma unroll
        for (int r = 0; r < 8; ++r) kk[r] = f2key(Sc[(jj * 8 + r) * 68 + e]);
        uint4 v0 = {kk[0], kk[1], kk[2], kk[3]}, v1 = {kk[4], kk[5], kk[6], kk[7]};
        unsigned* dst = KeyT + (size_t)e * BS + T0 + jj * 8;
        *(uint4*)dst = v0;
        *(uint4*)(dst + 4) = v1;
    }
}

// ---------------------------------------------------------------------------
// K2: per-expert exact C-th-largest fp32 key via register-resident 32-step
// binary search (no histograms, no atomics in the search). Then one pass:
// count definite-ins (> khi), collect candidates in [klo, khi].
// ---------------------------------------------------------------------------
__global__ __launch_bounds__(1024) void k2_select(const unsigned* __restrict__ KeyT,
                                                  const int* __restrict__ Cptr,
                                                  unsigned* __restrict__ khi_g,
                                                  int* __restrict__ needed_g,
                                                  int* __restrict__ ncand_g,
                                                  int* __restrict__ cand_g) {
    const int e = blockIdx.x, tid = threadIdx.x;
    const int wid = tid >> 6, lane = tid & 63;
    const int C = *Cptr;
    const unsigned* col = KeyT + (size_t)e * BS;

    unsigned key[16];
#pragma unroll
    for (int j = 0; j < 16; ++j) key[j] = col[j * 1024 + tid];

    __shared__ int sred[16];
    __shared__ int s_tot;
    __shared__ int s_nc;

    unsigned K = 0;
    for (int b = 31; b >= 0; --b) {
        const unsigned T = K | (1u << b);
        int c = 0;
#pragma unroll
        for (int j = 0; j < 16; ++j) c += (key[j] >= T);
#pragma unroll
        for (int off = 32; off; off >>= 1) c += __shfl_xor(c, off);
        if (lane == 0) sred[wid] = c;
        __syncthreads();
        if (wid == 0) {
            int v = (lane < 16) ? sred[lane] : 0;
            v += __shfl_xor(v, 1); v += __shfl_xor(v, 2);
            v += __shfl_xor(v, 4); v += __shfl_xor(v, 8);
            if (lane == 0) s_tot = v;
        }
        __syncthreads();
        if (s_tot >= C) K = T;
        __syncthreads();
    }

    const float vT = key2f(K);
    const unsigned khi = f2key(vT + DELTA);
    const unsigned klo = f2key(vT - DELTA);

    int nd = 0;
#pragma unroll
    for (int j = 0; j < 16; ++j) nd += (key[j] > khi);
#pragma unroll
    for (int off = 32; off; off >>= 1) nd += __shfl_xor(nd, off);
    if (lane == 0) sred[wid] = nd;
    if (tid == 0) s_nc = 0;
    __syncthreads();
    if (wid == 0) {
        int v = (lane < 16) ? sred[lane] : 0;
        v += __shfl_xor(v, 1); v += __shfl_xor(v, 2);
        v += __shfl_xor(v, 4); v += __shfl_xor(v, 8);
        if (lane == 0) s_tot = v;
    }
    __syncthreads();
#pragma unroll
    for (int j = 0; j < 16; ++j) {
        if (key[j] >= klo && key[j] <= khi) {
            const int pos = atomicAdd(&s_nc, 1);
            if (pos < CAP) cand_g[(size_t)e * CAP + pos] = j * 1024 + tid;
        }
    }
    __syncthreads();
    if (tid == 0) {
        khi_g[e] = khi;
        needed_g[e] = C - s_tot;
        ncand_g[e] = (s_nc < CAP) ? s_nc : CAP;
    }
}

// ---------------------------------------------------------------------------
// K2b: exact fp64 dots for boundary candidates (wave-parallel); pick
// top-'needed' by (fp64 desc, idx asc); set winner bits.
// ---------------------------------------------------------------------------
__global__ __launch_bounds__(256) void k2b_resolve(const float* __restrict__ A,
                                                   const float* __restrict__ W,
                                                   const int* __restrict__ needed_g,
                                                   const int* __restrict__ ncand_g,
                                                   const int* __restrict__ cand_g,
                                                   unsigned* __restrict__ win_g) {
    const int e = blockIdx.x, tid = threadIdx.x, w = tid >> 6, lane = tid & 63;
    int n = ncand_g[e]; if (n > CAP) n = CAP;
    int need = needed_g[e]; if (need > n) need = n; if (need < 0) need = 0;
    __shared__ double sval[CAP];
    __shared__ int sidx[CAP];
    const float* Wr = W + (size_t)e * HDIM;
    for (int c = w; c < n; c += 4) {
        const int t = cand_g[(size_t)e * CAP + c];
        const float* Ar = A + (size_t)t * HDIM;
        double ps = 0.0;
#pragma unroll 8
        for (int j = 0; j < HDIM / 64; ++j)
            ps += (double)Ar[j * 64 + lane] * (double)Wr[j * 64 + lane];
#pragma unroll
        for (int off = 32; off; off >>= 1) ps += __shfl_xor(ps, off);
        if (lane == 0) { sval[c] = ps; sidx[c] = t; }
    }
    __syncthreads();
    if (tid == 0) {
        for (int s = 0; s < need; ++s) {
            int best = -1;
            for (int c = 0; c < n; ++c) {
                if (sidx[c] < 0) continue;
                if (best < 0 || sval[c] > sval[best] ||
                    (sval[c] == sval[best] && sidx[c] < sidx[best]))
                    best = c;
            }
            const int t = sidx[best];
            win_g[(size_t)e * CAP + (t >> 5)] |= (1u << (t & 31));
            sidx[best] = -1;
        }
    }
}

// ---------------------------------------------------------------------------
// K3: per-token softmax+mask+renorm (single reduction pass; |logit| small).
// map = (key > khi) | winner bit. fp64 importance via atomics.
// ---------------------------------------------------------------------------
__global__ __launch_bounds__(256) void k3_softmax(const float* __restrict__ Lg,
                                                  const unsigned* __restrict__ khi_g,
                                                  const unsigned* __restrict__ win_g,
                                                  float* __restrict__ probs,
                                                  float* __restrict__ out_map,
                                                  double* __restrict__ imp_g) {
    const int tid = threadIdx.x, w = tid >> 6, e = tid & 63, b = blockIdx.x;
    __shared__ unsigned skhi[64];
    __shared__ double sim[4][64];
    if (tid < 64) skhi[tid] = khi_g[tid];
    __syncthreads();
    const unsigned kh = skhi[e];
    double accim = 0.0;
#pragma unroll
    for (int it = 0; it < 4; ++it) {
        const int t = b * 16 + w * 4 + it;
        const float x = Lg[(size_t)t * NE + e];
        const unsigned key = f2key(x);
        float mfl;
        if (key > kh) mfl = 1.f;
        else mfl = (float)((win_g[(size_t)e * CAP + (t >> 5)] >> (t & 31)) & 1u);
        const float ev = expf(x);
        const float evm = ev * mfl;
        float s1 = ev, s2 = evm;
#pragma unroll
        for (int off = 32; off; off >>= 1) {
            s1 += __shfl_xor(s1, off);
            s2 += __shfl_xor(s2, off);
        }
        const float o = evm / (s2 + 1e-6f * s1);  // == (p*m)/(sum(p*m)+eps)
        probs[(size_t)t * NE + e] = o;
        out_map[(size_t)t * NE + e] = mfl;
        accim += (double)o;
    }
    sim[w][e] = accim;
    __syncthreads();
    if (w == 0) atomicAdd(&imp_g[e], sim[0][e] + sim[1][e] + sim[2][e] + sim[3][e]);
}

// ---------------------------------------------------------------------------
// K4: aux = (std(importance,ddof=1)/(mean+eps))^2 ; load_loss == 0 exactly.
// ---------------------------------------------------------------------------
__global__ __launch_bounds__(64) void k4_aux(const double* __restrict__ imp_g,
                                             float* __restrict__ out_aux) {
    const int e = threadIdx.x;
    const double v = imp_g[e];
    double s = v;
#pragma unroll
    for (int off = 32; off; off >>= 1) s += __shfl_xor(s, off);
    const double mean = s / 64.0;
    const double d = v - mean;
    double ss = d * d;
#pragma unroll
    for (int off = 32; off; off >>= 1) ss += __shfl_xor(ss, off);
    if (e == 0) {
        const double var = ss / 63.0;
        const double dn = mean + 1e-6;
        out_aux[0] = (float)(var / (dn * dn));
    }
}

extern "C" void kernel_launch(void* const* d_in, const int* in_sizes, int n_in,
                              void* d_out, int out_size, void* d_ws, size_t ws_size,
                              hipStream_t stream) {
    const float* A = (const float*)d_in[0];
    const float* W = (const float*)d_in[1];
    const int* Cptr = (const int*)d_in[2];

    float* out_probs = (float*)d_out;
    float* out_map = out_probs + (size_t)BS * NE;
    float* out_aux = out_map + (size_t)BS * NE;

    char* wsb = (char*)d_ws;
    float*          Lg     = (float*)wsb;                                   // 4 MB
    unsigned*       KeyT   = (unsigned*)(wsb + (4ull << 20));               // 4 MB
    unsigned short* Wh     = (unsigned short*)(wsb + (8ull << 20));         // 512 KB
    unsigned short* Wl     = (unsigned short*)(wsb + (8ull << 20) + (512ull << 10));
    int*            cand   = (int*)(wsb + (9ull << 20));                    // 128 KB
    unsigned*       win    = (unsigned*)(wsb + (9ull << 20) + (128ull << 10));  // 128 KB
    unsigned*       khi_g  = (unsigned*)(wsb + (9ull << 20) + (256ull << 10));
    int*            needed = (int*)(wsb + (9ull << 20) + (257ull << 10));
    int*            ncand  = (int*)(wsb + (9ull << 20) + (258ull << 10));
    double*         imp_g  = (double*)(wsb + (9ull << 20) + (259ull << 10));

    k0_init<<<256, 256, 0, stream>>>(W, Wh, Wl, win, imp_g);
    k1_gemm<<<BS / TT, 512, 0, stream>>>(A, Wh, Wl, Lg, KeyT);
    k2_select<<<NE, 1024, 0, stream>>>(KeyT, Cptr, khi_g, needed, ncand, cand);
    k2b_resolve<<<NE, 256, 0, stream>>>(A, W, needed, ncand, cand, win);
    k3_softmax<<<BS / 16, 256, 0, stream>>>(Lg, khi_g, win, out_probs, out_map, imp_g);
    k4_aux<<<1, 64, 0, stream>>>(imp_g, out_aux);
}

// Round 5
// 464.046 us; speedup vs baseline: 1.3679x; 1.0213x over previous
//
#include <hip/hip_runtime.h>
#include <hip/hip_bf16.h>

#define BS 16384    // B*S tokens
#define HDIM 4096   // hidden dim
#define NE 64       // experts
#define KC 64       // K-chunk per LDS stage
#define TT 32       // tokens per block (K1)
#define CAP 512     // max boundary candidates per expert
#define DELTA 2e-3f // bf16-split GEMM error margin (actual err ~2e-5 rms)

typedef __bf16 bf16x8 __attribute__((ext_vector_type(8)));
typedef float f32x4 __attribute__((ext_vector_type(4)));
union Frag { uint4 q; bf16x8 v; };

__device__ inline unsigned f2key(float f) {
    unsigned u = __float_as_uint(f);
    return (u & 0x80000000u) ? ~u : (u | 0x80000000u);
}
__device__ inline float key2f(unsigned k) {
    unsigned u = (k & 0x80000000u) ? (k ^ 0x80000000u) : ~k;
    return __uint_as_float(u);
}
__device__ inline unsigned pack_hi(float a, float b) {  // bf16(a)|bf16(b)<<16 (trunc)
    return (__float_as_uint(a) >> 16) | (__float_as_uint(b) & 0xFFFF0000u);
}
__device__ inline float bf16_resid(float a) {  // a - trunc_bf16(a), exact
    return a - __uint_as_float(__float_as_uint(a) & 0xFFFF0000u);
}

// ---------------------------------------------------------------------------
// K0: convert W -> bf16 hi/lo; zero token-major winner bitmap.
// ---------------------------------------------------------------------------
__global__ __launch_bounds__(256) void k0_init(const float* __restrict__ W,
                                               unsigned short* __restrict__ Wh,
                                               unsigned short* __restrict__ Wl,
                                               unsigned long long* __restrict__ win_t) {
    const int gtid = blockIdx.x * 256 + threadIdx.x;  // 0..65535
    const size_t f = (size_t)gtid * 4;                // covers NE*HDIM = 262144
    float4 w = *(const float4*)(W + f);
    uint2 hh, ll;
    hh.x = pack_hi(w.x, w.y); hh.y = pack_hi(w.z, w.w);
    ll.x = pack_hi(bf16_resid(w.x), bf16_resid(w.y));
    ll.y = pack_hi(bf16_resid(w.z), bf16_resid(w.w));
    *(uint2*)(Wh + f) = hh;
    *(uint2*)(Wl + f) = ll;
    if (gtid < BS) win_t[gtid] = 0ull;
}

// ---------------------------------------------------------------------------
// K1: logits = A @ W^T via bf16-split MFMA (AhBh+AlBh+AhBl, 16x16x32).
// 32 tok x 64 exp tile, 256 thr (4 waves: 2 M-tiles x 2 N-halves), grid 512
// -> 2 blocks/CU (LDS 2x55296 B = 110.6 KB) for cross-block barrier overlap.
// Double-buffered LDS, one __syncthreads/chunk, register prefetch.
// Epilogue: Lg token-major + KeyT expert-major via LDS transpose.
// ---------------------------------------------------------------------------
__global__ __launch_bounds__(256, 2) void k1_gemm(const float* __restrict__ A,
                                                  const unsigned short* __restrict__ Wh,
                                                  const unsigned short* __restrict__ Wl,
                                                  float* __restrict__ Lg,
                                                  unsigned* __restrict__ KeyT) {
    // per buffer (13824 shorts): As_h[32][72] @0, As_l @2304, Ws_h[64][72] @4608,
    // Ws_l @9216. Two buffers = 27648 shorts = 55296 B.
    __shared__ __align__(16) unsigned short sbuf[2 * 13824];

    const int tid = threadIdx.x;
    const int T0 = blockIdx.x * TT;

    const int arow = tid >> 3, aseg = tid & 7;  // A staging: row 0..31, 8-float seg

    const int lane = tid & 63, w = tid >> 6;
    const int m = lane & 15, q = lane >> 4;
    const int wm = w & 1;   // M tile (16 tokens)
    const int wn = w >> 1;  // N half (32 experts)

    const float* Aprow = A + (size_t)(T0 + arow) * HDIM + aseg * 8;

    f32x4 acc[2] = {{0.f, 0.f, 0.f, 0.f}, {0.f, 0.f, 0.f, 0.f}};

    float4 pa0 = *(const float4*)(Aprow);
    float4 pa1 = *(const float4*)(Aprow + 4);
    uint4 pwh[2], pwl[2];
#pragma unroll
    for (int i = 0; i < 2; ++i) {
        const int u = i * 256 + tid;               // 0..511
        const int r = u >> 3, blk = u & 7;         // row 0..63, 8-short seg
        pwh[i] = *(const uint4*)(Wh + (size_t)r * HDIM + blk * 8);
        pwl[i] = *(const uint4*)(Wl + (size_t)r * HDIM + blk * 8);
    }

    // stage chunk 0 into buffer 0
    {
        unsigned short* B = sbuf;
        uint4 H, L;
        H.x = pack_hi(pa0.x, pa0.y); H.y = pack_hi(pa0.z, pa0.w);
        H.z = pack_hi(pa1.x, pa1.y); H.w = pack_hi(pa1.z, pa1.w);
        L.x = pack_hi(bf16_resid(pa0.x), bf16_resid(pa0.y));
        L.y = pack_hi(bf16_resid(pa0.z), bf16_resid(pa0.w));
        L.z = pack_hi(bf16_resid(pa1.x), bf16_resid(pa1.y));
        L.w = pack_hi(bf16_resid(pa1.z), bf16_resid(pa1.w));
        *(uint4*)(B + arow * 72 + aseg * 8) = H;
        *(uint4*)(B + 2304 + arow * 72 + aseg * 8) = L;
#pragma unroll
        for (int i = 0; i < 2; ++i) {
            const int u = i * 256 + tid;
            const int r = u >> 3, blk = u & 7;
            *(uint4*)(B + 4608 + r * 72 + blk * 8) = pwh[i];
            *(uint4*)(B + 9216 + r * 72 + blk * 8) = pwl[i];
        }
    }

    for (int c = 0; c < HDIM / KC; ++c) {
        if (c + 1 < HDIM / KC) {  // issue prefetch for chunk c+1
            const int c0 = (c + 1) * KC;
            pa0 = *(const float4*)(Aprow + c0);
            pa1 = *(const float4*)(Aprow + c0 + 4);
#pragma unroll
            for (int i = 0; i < 2; ++i) {
                const int u = i * 256 + tid;
                const int r = u >> 3, blk = u & 7;
                pwh[i] = *(const uint4*)(Wh + (size_t)r * HDIM + c0 + blk * 8);
                pwl[i] = *(const uint4*)(Wl + (size_t)r * HDIM + c0 + blk * 8);
            }
        }
        __syncthreads();  // buf[c&1] visible; prior reads of buf[(c+1)&1] done
        {
            const unsigned short* B = sbuf + (c & 1) * 13824;
            const unsigned short* Ash = B + (wm * 16 + m) * 72;
            const unsigned short* Asl = Ash + 2304;
#pragma unroll
            for (int kh = 0; kh < 2; ++kh) {
                const int ko = kh * 32 + q * 8;
                Frag ah, al;
                ah.q = *(const uint4*)(Ash + ko);
                al.q = *(const uint4*)(Asl + ko);
#pragma unroll
                for (int nt = 0; nt < 2; ++nt) {
                    const int er = wn * 32 + nt * 16 + m;
                    Frag bh, bl;
                    bh.q = *(const uint4*)(B + 4608 + er * 72 + ko);
                    bl.q = *(const uint4*)(B + 9216 + er * 72 + ko);
                    acc[nt] = __builtin_amdgcn_mfma_f32_16x16x32_bf16(ah.v, bh.v, acc[nt], 0, 0, 0);
                    acc[nt] = __builtin_amdgcn_mfma_f32_16x16x32_bf16(al.v, bh.v, acc[nt], 0, 0, 0);
                    acc[nt] = __builtin_amdgcn_mfma_f32_16x16x32_bf16(ah.v, bl.v, acc[nt], 0, 0, 0);
                }
            }
        }
        if (c + 1 < HDIM / KC) {  // stage chunk c+1 into the other buffer
            unsigned short* B = sbuf + ((c + 1) & 1) * 13824;
            uint4 H, L;
            H.x = pack_hi(pa0.x, pa0.y); H.y = pack_hi(pa0.z, pa0.w);
            H.z = pack_hi(pa1.x, pa1.y); H.w = pack_hi(pa1.z, pa1.w);
            L.x = pack_hi(bf16_resid(pa0.x), bf16_resid(pa0.y));
            L.y = pack_hi(bf16_resid(pa0.z), bf16_resid(pa0.w));
            L.z = pack_hi(bf16_resid(pa1.x), bf16_resid(pa1.y));
            L.w = pack_hi(bf16_resid(pa1.z), bf16_resid(pa1.w));
            *(uint4*)(B + arow * 72 + aseg * 8) = H;
            *(uint4*)(B + 2304 + arow * 72 + aseg * 8) = L;
#pragma unroll
            for (int i = 0; i < 2; ++i) {
                const int u = i * 256 + tid;
                const int r = u >> 3, blk = u & 7;
                *(uint4*)(B + 4608 + r * 72 + blk * 8) = pwh[i];
                *(uint4*)(B + 9216 + r * 72 + blk * 8) = pwl[i];
            }
        }
    }

    // Epilogue: Lg direct, KeyT via LDS transpose (coalesced per expert)
    __syncthreads();
    float* Sc = (float*)sbuf;  // [32][68] floats = 8704 B
#pragma unroll
    for (int nt = 0; nt < 2; ++nt) {
        const int e = wn * 32 + nt * 16 + m;  // C/D: col = lane&15
#pragma unroll
        for (int r = 0; r < 4; ++r) {
            const int tl = wm * 16 + q * 4 + r;  // C/D: row = quad*4+reg
            const float v = acc[nt][r];
            Sc[tl * 68 + e] = v;
            Lg[(size_t)(T0 + tl) * NE + e] = v;
        }
    }
    __syncthreads();
    {
        const int e = tid >> 2, jj = tid & 3;  // 8 tokens per thread
        unsigned kk[8];
#pragma unroll
        for (int r = 0; r < 8; ++r) kk[r] = f2key(Sc[(jj * 8 + r) * 68 + e]);
        uint4 v0 = {kk[0], kk[1], kk[2], kk[3]}, v1 = {kk[4], kk[5], kk[6], kk[7]};
        unsigned* dst = KeyT + (size_t)e * BS + T0 + jj * 8;
        *(uint4*)dst = v0;
        *(uint4*)(dst + 4) = v1;
    }
}

// ---------------------------------------------------------------------------
// K2: per-expert exact C-th-largest fp32 key via register-resident 32-step
// binary search (keys live in 16 VGPRs/thread). Then one pass: count
// definite-ins (> khi), collect candidates in [klo, khi].
// ---------------------------------------------------------------------------
__global__ __launch_bounds__(1024) void k2_select(const unsigned* __restrict__ KeyT,
                                                  const int* __restrict__ Cptr,
                                                  unsigned* __restrict__ khi_g,
                                                  int* __restrict__ needed_g,
                                                  int* __restrict__ ncand_g,
                                                  int* __restrict__ cand_g) {
    const int e = blockIdx.x, tid = threadIdx.x;
    const int wid = tid >> 6, lane = tid & 63;
    const int C = *Cptr;
    const unsigned* col = KeyT + (size_t)e * BS;

    unsigned key[16];
#pragma unroll
    for (int j = 0; j < 16; ++j) key[j] = col[j * 1024 + tid];

    __shared__ int sred[16];
    __shared__ int s_tot;
    __shared__ int s_nc;

    unsigned K = 0;
    for (int b = 31; b >= 0; --b) {
        const unsigned T = K | (1u << b);
        int c = 0;
#pragma unroll
        for (int j = 0; j < 16; ++j) c += (key[j] >= T);
#pragma unroll
        for (int off = 32; off; off >>= 1) c += __shfl_xor(c, off);
        if (lane == 0) sred[wid] = c;
        __syncthreads();
        if (wid == 0) {
            int v = (lane < 16) ? sred[lane] : 0;
            v += __shfl_xor(v, 1); v += __shfl_xor(v, 2);
            v += __shfl_xor(v, 4); v += __shfl_xor(v, 8);
            if (lane == 0) s_tot = v;
        }
        __syncthreads();
        if (s_tot >= C) K = T;
        __syncthreads();
    }

    const float vT = key2f(K);
    const unsigned khi = f2key(vT + DELTA);
    const unsigned klo = f2key(vT - DELTA);

    int nd = 0;
#pragma unroll
    for (int j = 0; j < 16; ++j) nd += (key[j] > khi);
#pragma unroll
    for (int off = 32; off; off >>= 1) nd += __shfl_xor(nd, off);
    if (lane == 0) sred[wid] = nd;
    if (tid == 0) s_nc = 0;
    __syncthreads();
    if (wid == 0) {
        int v = (lane < 16) ? sred[lane] : 0;
        v += __shfl_xor(v, 1); v += __shfl_xor(v, 2);
        v += __shfl_xor(v, 4); v += __shfl_xor(v, 8);
        if (lane == 0) s_tot = v;
    }
    __syncthreads();
#pragma unroll
    for (int j = 0; j < 16; ++j) {
        if (key[j] >= klo && key[j] <= khi) {
            const int pos = atomicAdd(&s_nc, 1);
            if (pos < CAP) cand_g[(size_t)e * CAP + pos] = j * 1024 + tid;
        }
    }
    __syncthreads();
    if (tid == 0) {
        khi_g[e] = khi;
        needed_g[e] = C - s_tot;
        ncand_g[e] = (s_nc < CAP) ? s_nc : CAP;
    }
}

// ---------------------------------------------------------------------------
// K2b: exact fp64 dots for boundary candidates (wave-parallel); pick
// top-'needed' by (fp64 desc, idx asc); set bits in token-major bitmap.
// ---------------------------------------------------------------------------
__global__ __launch_bounds__(256) void k2b_resolve(const float* __restrict__ A,
                                                   const float* __restrict__ W,
                                                   const int* __restrict__ needed_g,
                                                   const int* __restrict__ ncand_g,
                                                   const int* __restrict__ cand_g,
                                                   unsigned long long* __restrict__ win_t) {
    const int e = blockIdx.x, tid = threadIdx.x, w = tid >> 6, lane = tid & 63;
    int n = ncand_g[e]; if (n > CAP) n = CAP;
    int need = needed_g[e]; if (need > n) need = n; if (need < 0) need = 0;
    __shared__ double sval[CAP];
    __shared__ int sidx[CAP];
    const float* Wr = W + (size_t)e * HDIM;
    for (int c = w; c < n; c += 4) {
        const int t = cand_g[(size_t)e * CAP + c];
        const float* Ar = A + (size_t)t * HDIM;
        double ps = 0.0;
#pragma unroll 8
        for (int j = 0; j < HDIM / 64; ++j)
            ps += (double)Ar[j * 64 + lane] * (double)Wr[j * 64 + lane];
#pragma unroll
        for (int off = 32; off; off >>= 1) ps += __shfl_xor(ps, off);
        if (lane == 0) { sval[c] = ps; sidx[c] = t; }
    }
    __syncthreads();
    if (tid == 0) {
        for (int s = 0; s < need; ++s) {
            int best = -1;
            for (int c = 0; c < n; ++c) {
                if (sidx[c] < 0) continue;
                if (best < 0 || sval[c] > sval[best] ||
                    (sval[c] == sval[best] && sidx[c] < sidx[best]))
                    best = c;
            }
            const int t = sidx[best];
            atomicOr(&win_t[t], 1ull << e);
            sidx[best] = -1;
        }
    }
}

// ---------------------------------------------------------------------------
// K3: per-token softmax+mask+renorm (single reduction pass; |logit| small).
// map = (key > khi) | token-major winner bit. Per-block fp64 importance
// partials (no global atomics).
// ---------------------------------------------------------------------------
__global__ __launch_bounds__(256) void k3_softmax(const float* __restrict__ Lg,
                                                  const unsigned* __restrict__ khi_g,
                                                  const unsigned long long* __restrict__ win_t,
                                                  float* __restrict__ probs,
                                                  float* __restrict__ out_map,
                                                  double* __restrict__ imp_partial) {
    const int tid = threadIdx.x, w = tid >> 6, e = tid & 63, b = blockIdx.x;
    __shared__ unsigned skhi[64];
    __shared__ double sim[4][64];
    if (tid < 64) skhi[tid] = khi_g[tid];
    __syncthreads();
    const unsigned kh = skhi[e];
    double accim = 0.0;
#pragma unroll
    for (int it = 0; it < 16; ++it) {
        const int t = b * 64 + it * 4 + w;
        const float x = Lg[(size_t)t * NE + e];
        const unsigned key = f2key(x);
        float mfl;
        if (key > kh) mfl = 1.f;
        else mfl = (float)((win_t[t] >> e) & 1ull);
        const float ev = expf(x);
        const float evm = ev * mfl;
        float s1 = ev, s2 = evm;
#pragma unroll
        for (int off = 32; off; off >>= 1) {
            s1 += __shfl_xor(s1, off);
            s2 += __shfl_xor(s2, off);
        }
        const float o = evm / (s2 + 1e-6f * s1);  // == (p*m)/(sum(p*m)+eps)
        probs[(size_t)t * NE + e] = o;
        out_map[(size_t)t * NE + e] = mfl;
        accim += (double)o;
    }
    sim[w][e] = accim;
    __syncthreads();
    if (w == 0)
        imp_partial[(size_t)b * NE + e] = sim[0][e] + sim[1][e] + sim[2][e] + sim[3][e];
}

// ---------------------------------------------------------------------------
// K4: reduce importance partials; aux = (std(imp,ddof=1)/(mean+eps))^2.
// load == C exactly per expert -> load_loss == 0.
// ---------------------------------------------------------------------------
__global__ __launch_bounds__(64) void k4_aux(const double* __restrict__ imp_partial,
                                             float* __restrict__ out_aux) {
    const int e = threadIdx.x;
    double v = 0.0;
    for (int b = 0; b < 256; ++b) v += imp_partial[(size_t)b * NE + e];
    double s = v;
#pragma unroll
    for (int off = 32; off; off >>= 1) s += __shfl_xor(s, off);
    const double mean = s / 64.0;
    const double d = v - mean;
    double ss = d * d;
#pragma unroll
    for (int off = 32; off; off >>= 1) ss += __shfl_xor(ss, off);
    if (e == 0) {
        const double var = ss / 63.0;
        const double dn = mean + 1e-6;
        out_aux[0] = (float)(var / (dn * dn));
    }
}

extern "C" void kernel_launch(void* const* d_in, const int* in_sizes, int n_in,
                              void* d_out, int out_size, void* d_ws, size_t ws_size,
                              hipStream_t stream) {
    const float* A = (const float*)d_in[0];
    const float* W = (const float*)d_in[1];
    const int* Cptr = (const int*)d_in[2];

    float* out_probs = (float*)d_out;
    float* out_map = out_probs + (size_t)BS * NE;
    float* out_aux = out_map + (size_t)BS * NE;

    char* wsb = (char*)d_ws;
    float*              Lg     = (float*)wsb;                                  // 4 MB
    unsigned*           KeyT   = (unsigned*)(wsb + (4ull << 20));              // 4 MB
    unsigned short*     Wh     = (unsigned short*)(wsb + (8ull << 20));        // 512 KB
    unsigned short*     Wl     = (unsigned short*)(wsb + (8ull << 20) + (512ull << 10));
    int*                cand   = (int*)(wsb + (9ull << 20));                   // 128 KB
    unsigned long long* win_t  = (unsigned long long*)(wsb + (9ull << 20) + (128ull << 10)); // 128 KB
    unsigned*           khi_g  = (unsigned*)(wsb + (9ull << 20) + (256ull << 10));
    int*                needed = (int*)(wsb + (9ull << 20) + (257ull << 10));
    int*                ncand  = (int*)(wsb + (9ull << 20) + (258ull << 10));
    double*             imp_p  = (double*)(wsb + (9ull << 20) + (512ull << 10)); // 128 KB

    k0_init<<<256, 256, 0, stream>>>(W, Wh, Wl, win_t);
    k1_gemm<<<BS / TT, 256, 0, stream>>>(A, Wh, Wl, Lg, KeyT);
    k2_select<<<NE, 1024, 0, stream>>>(KeyT, Cptr, khi_g, needed, ncand, cand);
    k2b_resolve<<<NE, 256, 0, stream>>>(A, W, needed, ncand, cand, win_t);
    k3_softmax<<<BS / 64, 256, 0, stream>>>(Lg, khi_g, win_t, out_probs, out_map, imp_p);
    k4_aux<<<1, 64, 0, stream>>>(imp_p, out_aux);
}